// Round 7
// baseline (385.017 us; speedup 1.0000x reference)
//
#include <hip/hip_runtime.h>
#include <stdint.h>

#define M_ROWS 4096
#define N_COLS 16384
#define K_HARD 163          // int(0.01 * (16384 - 1))
#define DELTA_W 5.0f
#define THREADS 1024
#define NWAVES  16
#define RPB     8           // rows per block
#define GRID    (M_ROWS / RPB)   // 512 blocks -> 2/CU, fat 512KB dense streams
#define THRESH  2.0f
#define KEY_MIN 0xC0000000u // f2key(2.0f)
#define SEGC    64          // per (wave,row) candidate cap; mean ~23, sd ~4.7 -> 8.7 sigma

__device__ __forceinline__ uint32_t f2key(float x) {
    uint32_t u = __float_as_uint(x);
    return u ^ (uint32_t)(((int32_t)u >> 31) | 0x80000000u);
}
__device__ __forceinline__ float key2f(uint32_t k) {
    uint32_t u = (k & 0x80000000u) ? (k & 0x7fffffffu) : ~k;
    return __uint_as_float(u);
}
__device__ __forceinline__ float softplus_f(float x) {
    return fmaxf(x, 0.0f) + log1pf(__expf(-fabsf(x)));
}

// Wave-local pivot scan over 1024 ascending bins: find bin P with
// count(bins > P) < K <= count(bins >= P). pivot=P, krem=K-count(bins>P).
// Requires sum(bins) >= K >= 1. All 64 lanes participate.
__device__ __forceinline__ void wscan1024(const uint32_t* h, int lane, int K,
                                          int& pivot, int& krem) {
    int c[16]; int S = 0;
#pragma unroll
    for (int q = 0; q < 16; ++q) { c[q] = (int)h[lane * 16 + q]; S += c[q]; }
    int suf = S;
    for (int off = 1; off < 64; off <<= 1) {
        int y = __shfl_down(suf, off);
        if (lane + off < 64) suf += y;
    }
    int run = suf - S;                     // count in bins strictly above mine
    int enc = 0;
#pragma unroll
    for (int b = 15; b >= 0; --b) {
        const int cc = c[b];
        if (run < K && run + cc >= K) enc = ((lane * 16 + b + 1) << 8) | (K - run);
        run += cc;
    }
    for (int off = 1; off < 64; off <<= 1) enc = max(enc, __shfl_xor(enc, off));
    pivot = (enc >> 8) - 1; krem = enc & 255;
}

// Wave-local exact full-row top-K fallback (never taken on N(0,1) data).
// Returns row softplus-sum on lane 0.
__device__ float wave_fallback(const float4* row4, int tgt, uint32_t* hrow, int lane) {
    uint32_t pref = 0; int K = K_HARD;
    for (int pass = 0; pass < 3; ++pass) {
        const int shift = 22 - 10 * pass;
        for (int q = 0; q < 16; ++q) hrow[q * 64 + lane] = 0;
        for (int s2 = 0; s2 < 64; ++s2) {
            const float4 v = row4[s2 * 64 + lane];
            const int j0 = (s2 * 64 + lane) * 4;
            const float e[4] = {v.x, v.y, v.z, v.w};
#pragma unroll
            for (int q = 0; q < 4; ++q) {
                if (j0 + q == tgt) continue;
                const uint32_t k = f2key(e[q]);
                if (pass == 0 || (k >> (shift + 10)) == pref)
                    atomicAdd(&hrow[(k >> shift) & 1023u], 1u);
            }
        }
        int pv, kr; wscan1024(hrow, lane, K, pv, kr);
        pref = (pref << 10) | (uint32_t)pv; K = kr;
    }
    // final 2 bits
    for (int q = 0; q < 16; ++q) hrow[q * 64 + lane] = 0;
    for (int s2 = 0; s2 < 64; ++s2) {
        const float4 v = row4[s2 * 64 + lane];
        const int j0 = (s2 * 64 + lane) * 4;
        const float e[4] = {v.x, v.y, v.z, v.w};
#pragma unroll
        for (int q = 0; q < 4; ++q) {
            if (j0 + q == tgt) continue;
            const uint32_t k = f2key(e[q]);
            if ((k >> 2) == pref) atomicAdd(&hrow[k & 3u], 1u);
        }
    }
    int piv = 0, tie = K;
    { int run = 0;
      for (int b2 = 3; b2 >= 0; --b2) {
          const int cc = (int)hrow[b2];
          if (run < K && run + cc >= K) { piv = b2; tie = K - run; }
          run += cc;
      } }
    const uint32_t T = (pref << 2) | (uint32_t)piv;
    float sum = 0.0f;
    for (int s2 = 0; s2 < 64; ++s2) {
        const float4 v = row4[s2 * 64 + lane];
        const int j0 = (s2 * 64 + lane) * 4;
        const float e[4] = {v.x, v.y, v.z, v.w};
#pragma unroll
        for (int q = 0; q < 4; ++q) {
            if (j0 + q == tgt) continue;
            const uint32_t k = f2key(e[q]);
            if (k > T) sum += softplus_f(e[q]);
        }
    }
    for (int off = 32; off; off >>= 1) sum += __shfl_down(sum, off);
    if (lane == 0) sum += (float)tie * softplus_f(key2f(T));
    return sum;   // valid on lane 0
}

__global__ __launch_bounds__(THREADS, 8) void mmcl_main(
        const float* __restrict__ inputs,
        const int* __restrict__ targets,
        float* __restrict__ partial) {
    __shared__ uint32_t s_seg[NWAVES][RPB][SEGC];   // 32 KB
    __shared__ uint32_t s_hist[RPB][1024];          // 32 KB
    __shared__ int s_cnt[NWAVES][RPB];              // 512 B

    const int b = blockIdx.x;
    const int t = threadIdx.x;
    const int lane = t & 63;
    const int w = t >> 6;
    const float4* in4 = (const float4*)inputs;
    const int gbase = b * (RPB * 4096);             // float4-group base

    // ---- Phase A: dense in-order stream of this block's 512 KB region ----
    for (int r = 0; r < RPB; ++r) {
        int wcount = 0;
#pragma unroll
        for (int ii = 0; ii < 4; ++ii) {
            const float4 v = in4[gbase + (r * 4 + ii) * 1024 + t];
            const float e[4] = {v.x, v.y, v.z, v.w};
            const int n = (v.x >= THRESH) + (v.y >= THRESH) +
                          (v.z >= THRESH) + (v.w >= THRESH);
            int inc = n;
            for (int off = 1; off < 64; off <<= 1) {
                int y = __shfl_up(inc, off);
                if (lane >= off) inc += y;
            }
            int base = wcount + inc - n;
            int j = 0;
#pragma unroll
            for (int q = 0; q < 4; ++q) {
                if (e[q] >= THRESH) {
                    const int d = base + j;
                    if (d < SEGC) s_seg[w][r][d] = f2key(e[q]);
                    ++j;
                }
            }
            wcount += __shfl(inc, 63);
        }
        if (lane == 0) s_cnt[w][r] = wcount;
    }
    __syncthreads();   // the ONLY block barrier

    // ---- Phase B: wave w < RPB selects row w, fully wave-local ----
    if (w < RPB) {
        const int r = w;
        const int grow = b * RPB + r;
        const int tgt = targets[grow];
        const float pos = inputs[(size_t)grow * N_COLS + tgt];
        const uint32_t tkey = f2key(pos);
        const float4* row4 = (const float4*)(inputs + (size_t)grow * N_COLS);
        uint32_t* hrow = &s_hist[r][0];

        bool fb = false;
        for (int s = 0; s < NWAVES; ++s) fb |= ((int)s_cnt[s][r] > SEGC);

        // remove one instance of the positive's key (bit-equal interchangeable)
        if (!fb && pos >= THRESH) {
            bool removed = false;
            for (int s = 0; s < NWAVES && !removed; ++s) {
                const int cc = (int)s_cnt[s][r];
                const uint32_t k = (lane < cc) ? s_seg[s][r][lane] : (tkey + 1u);
                const unsigned long long m = __ballot(lane < cc && k == tkey);
                if (m) {
                    const int f = __ffsll(m) - 1;
                    if (lane == 0) {
                        s_seg[s][r][f] = s_seg[s][r][cc - 1];
                        s_cnt[s][r] = cc - 1;
                    }
                    removed = true;
                }
            }
        }
        int ncand = 0;
        for (int s = 0; s < NWAVES; ++s) ncand += (int)s_cnt[s][r];
        if (ncand < K_HARD) fb = true;

        float sum;
        if (!fb) {
            // L1: bits [29:20] of (key - KEY_MIN)
            for (int q = 0; q < 16; ++q) hrow[q * 64 + lane] = 0;
            for (int s = 0; s < NWAVES; ++s) {
                const int cc = (int)s_cnt[s][r];
                if (lane < cc)
                    atomicAdd(&hrow[(s_seg[s][r][lane] - KEY_MIN) >> 20], 1u);
            }
            int p1, k1; wscan1024(hrow, lane, K_HARD, p1, k1);
            // L2: bits [19:10] among L1-pivot members
            for (int q = 0; q < 16; ++q) hrow[q * 64 + lane] = 0;
            for (int s = 0; s < NWAVES; ++s) {
                const int cc = (int)s_cnt[s][r];
                if (lane < cc) {
                    const uint32_t d = s_seg[s][r][lane] - KEY_MIN;
                    if ((int)(d >> 20) == p1) atomicAdd(&hrow[(d >> 10) & 1023u], 1u);
                }
            }
            int p2, k2; wscan1024(hrow, lane, k1, p2, k2);
            // L3: bits [9:0]
            const uint32_t pref2 = ((uint32_t)p1 << 10) | (uint32_t)p2;
            for (int q = 0; q < 16; ++q) hrow[q * 64 + lane] = 0;
            for (int s = 0; s < NWAVES; ++s) {
                const int cc = (int)s_cnt[s][r];
                if (lane < cc) {
                    const uint32_t d = s_seg[s][r][lane] - KEY_MIN;
                    if ((d >> 10) == pref2) atomicAdd(&hrow[d & 1023u], 1u);
                }
            }
            int p3, k3; wscan1024(hrow, lane, k2, p3, k3);
            const uint32_t T = KEY_MIN +
                (((uint32_t)p1 << 20) | ((uint32_t)p2 << 10) | (uint32_t)p3);
            sum = 0.0f;
            for (int s = 0; s < NWAVES; ++s) {
                const int cc = (int)s_cnt[s][r];
                if (lane < cc) {
                    const uint32_t k = s_seg[s][r][lane];
                    if (k > T) sum += softplus_f(key2f(k));
                }
            }
            for (int off = 32; off; off >>= 1) sum += __shfl_down(sum, off);
            if (lane == 0) sum += (float)k3 * softplus_f(key2f(T));
        } else {
            sum = wave_fallback(row4, tgt, hrow, lane);
        }

        if (lane == 0) {
            const float l_neg = sum / (float)K_HARD;
            partial[grow] = DELTA_W * softplus_f(-pos) + l_neg;
        }
    }
}

__global__ __launch_bounds__(256) void mmcl_reduce(
        const float* __restrict__ partial, float* __restrict__ out) {
    __shared__ float s_fw[4];
    const int t = threadIdx.x;
    float local = 0.0f;
    for (int i = t; i < M_ROWS; i += 256) local += partial[i];
    for (int off = 32; off; off >>= 1) local += __shfl_down(local, off);
    if ((t & 63) == 0) s_fw[t >> 6] = local;
    __syncthreads();
    if (t == 0)
        out[0] = (s_fw[0] + s_fw[1] + s_fw[2] + s_fw[3]) * (1.0f / (float)M_ROWS);
}

extern "C" void kernel_launch(void* const* d_in, const int* in_sizes, int n_in,
                              void* d_out, int out_size, void* d_ws, size_t ws_size,
                              hipStream_t stream) {
    const float* inputs = (const float*)d_in[0];
    const int* targets = (const int*)d_in[1];
    float* out = (float*)d_out;
    float* partial = (float*)d_ws;   // 16 KB, fully rewritten every launch
    mmcl_main<<<GRID, THREADS, 0, stream>>>(inputs, targets, partial);
    mmcl_reduce<<<1, 256, 0, stream>>>(partial, out);
}